// Round 2
// baseline (259.028 us; speedup 1.0000x reference)
//
#include <hip/hip_runtime.h>
#include <hip/hip_bf16.h>
#include <stdint.h>

// Problem constants (from reference): B=16384, F=32, D=64, H=2*D=128.
#define B_SZ 16384
#define F_SZ 32
#define D_SZ 64
#define H_SZ 128
#define RSTRIDE 72   // LDS row stride in shorts (64 + 8 pad) => 144 B: uniform bank load

typedef __attribute__((ext_vector_type(8))) short  short8;   // 8 x bf16 MFMA frag
typedef __attribute__((ext_vector_type(4))) float  float4v;  // MFMA acc
typedef __attribute__((ext_vector_type(4))) unsigned int uint4v;

// round-half-up f32->bf16, pack (lo -> bits[15:0], hi -> bits[31:16])
__device__ __forceinline__ unsigned int pkbf(float lo, float hi) {
  unsigned int ulo = __builtin_bit_cast(unsigned int, lo) + 0x8000u;
  unsigned int uhi = __builtin_bit_cast(unsigned int, hi) + 0x8000u;
  return __builtin_amdgcn_perm(uhi, ulo, 0x07060302u);
}

// Kernel 1: W1 [F][D][H] f32 -> w1t [F][H][D] bf16. Grid = F*4; block handles
// (f, 32-h chunk): reads 64 d x 32 h, LDS-transposes, writes bf16.
// Also packs {b1,w2} per h as one u32 (b1 hi16, w2 lo16).
__global__ __launch_bounds__(256) void ContMlp_prep(
    const float* __restrict__ W1, const float* __restrict__ b1,
    const float* __restrict__ W2, unsigned short* __restrict__ w1t,
    unsigned int* __restrict__ bw) {
  const int f  = blockIdx.x >> 2;
  const int hq = blockIdx.x & 3;
  const int h0 = hq * 32;
  const int t  = threadIdx.x;
  __shared__ float lds[D_SZ][33];
  const float* w1f = W1 + (size_t)f * (D_SZ * H_SZ);
#pragma unroll
  for (int i = 0; i < 8; ++i) {
    int idx = t + 256 * i;              // 0..2047
    int d = idx >> 5, hh = idx & 31;
    lds[d][hh] = w1f[d * H_SZ + h0 + hh];   // coalesced 128B runs
  }
  __syncthreads();
  unsigned short* o = w1t + (size_t)f * (H_SZ * D_SZ);
#pragma unroll
  for (int i = 0; i < 8; ++i) {
    int idx = t + 256 * i;
    int hh = idx >> 6, d = idx & 63;
    unsigned int u = __builtin_bit_cast(unsigned int, lds[d][hh]) + 0x8000u;
    o[(h0 + hh) * D_SZ + d] = (unsigned short)(u >> 16);
  }
  if (hq == 0 && t < H_SZ) {
    unsigned int ub = __builtin_bit_cast(unsigned int, b1[f * H_SZ + t]) + 0x8000u;
    unsigned int uw = __builtin_bit_cast(unsigned int, W2[f * H_SZ + t]) + 0x8000u;
    bw[f * H_SZ + t] = (ub & 0xFFFF0000u) | (uw >> 16);
  }
}

// Per-subtile compute: 16 batch rows x H via 8 t-tiles of mfma 16x16x32 bf16,
// K=D=64 (2 k-steps). A (weights) from LDS, B (r_) from registers. Epilogue
// folds per-t to keep acc liveness at 4 floats.
__device__ __forceinline__ void compute_sub(
    float4v c0, float4v c1, float4v c2, float4v c3,
    const unsigned short* w1l, const unsigned int* bwl,
    float b2f, int col, int quad, float* store_ptr) {
  unsigned int p0 = pkbf(c0.x, c0.y), p1 = pkbf(c0.z, c0.w);
  unsigned int p2 = pkbf(c1.x, c1.y), p3 = pkbf(c1.z, c1.w);
  unsigned int p4 = pkbf(c2.x, c2.y), p5 = pkbf(c2.z, c2.w);
  unsigned int p6 = pkbf(c3.x, c3.y), p7 = pkbf(c3.z, c3.w);
  uint4v bq0 = {p0, p1, p2, p3};
  uint4v bq1 = {p4, p5, p6, p7};
  short8 bf0 = __builtin_bit_cast(short8, bq0);
  short8 bf1 = __builtin_bit_cast(short8, bq1);

  float ysum = 0.f;
#pragma unroll
  for (int t = 0; t < 8; ++t) {
    const unsigned short* wrow = w1l + (col + 16 * t) * RSTRIDE + quad * 8;
    short8 a0 = *(const short8*)(wrow);
    short8 a1 = *(const short8*)(wrow + 32);
    float4v acc = {0.f, 0.f, 0.f, 0.f};
    acc = __builtin_amdgcn_mfma_f32_16x16x32_bf16(a0, bf0, acc, 0, 0, 0);
    acc = __builtin_amdgcn_mfma_f32_16x16x32_bf16(a1, bf1, acc, 0, 0, 0);
    uint4v bwv = *(const uint4v*)(bwl + 16 * t + quad * 4);  // broadcast reads
#pragma unroll
    for (int r = 0; r < 4; ++r) {
      unsigned int u = bwv[r];
      float b1v = __builtin_bit_cast(float, u & 0xFFFF0000u);
      float w2v = __builtin_bit_cast(float, u << 16);
      ysum = fmaf(fmaxf(acc[r] + b1v, 0.f), w2v, ysum);
    }
  }
  ysum += __shfl_xor(ysum, 16, 64);
  ysum += __shfl_xor(ysum, 32, 64);
  float y = fmaxf(ysum + b2f, 0.f);
  if (quad == 0) *store_ptr = y;
}

// Kernel 2: grid = 64 tiles x 32 f. Block = 4 waves x 64 rows each = 256 rows.
// Weights staged once in LDS (padded); r_ loads double-buffered across the
// 4 subtiles per wave. y written via parametrized address:
//   addr = f*y_fmul + row*y_rmul + y_cadd   (f-major ws OR interleaved out)
__global__ void ContMlp_main(
    const float* __restrict__ r_,
    const unsigned short* __restrict__ w1t, const unsigned int* __restrict__ bw,
    const float* __restrict__ b2, float* __restrict__ ydst,
    int y_fmul, int y_rmul, int y_cadd) {
  const int f    = blockIdx.x & 31;
  const int tile = blockIdx.x >> 5;
  const int w    = threadIdx.x >> 6;
  const int l    = threadIdx.x & 63;
  const int col  = l & 15;
  const int quad = l >> 4;

  __shared__ unsigned short w1l[H_SZ * RSTRIDE];
  __shared__ unsigned int   bwl[H_SZ];

  {  // stage 16 KB of bf16 weights, 16B chunks into padded rows
    const uint4v* src = (const uint4v*)(w1t + (size_t)f * (H_SZ * D_SZ));
#pragma unroll
    for (int i = 0; i < 4; ++i) {
      int ci = threadIdx.x + 256 * i;   // 0..1023
      int h = ci >> 3, dc = ci & 7;
      *(uint4v*)(w1l + h * RSTRIDE + dc * 8) = src[ci];
    }
    if (threadIdx.x < H_SZ) bwl[threadIdx.x] = bw[f * H_SZ + threadIdx.x];
  }
  __syncthreads();
  const float b2f = b2[f];

  const int row_w0 = tile * 256 + w * 64;           // wave's first row
  const float* rbase = r_ + (size_t)(row_w0 + col) * (F_SZ * D_SZ)
                          + f * D_SZ + quad * 8;

#define LOADSUB(S, N)                                                   \
  do {                                                                  \
    const float* p_ = rbase + (size_t)(S) * 16 * (F_SZ * D_SZ);         \
    N##0 = *(const float4v*)(p_);      N##1 = *(const float4v*)(p_ + 4);\
    N##2 = *(const float4v*)(p_ + 32); N##3 = *(const float4v*)(p_ + 36);\
  } while (0)

#define YPTR(S) (ydst + (size_t)f * y_fmul                               \
                     + (size_t)(row_w0 + (S)*16 + col) * y_rmul + y_cadd)

  float4v A0, A1, A2, A3, Bb0, Bb1, Bb2, Bb3;
  LOADSUB(0, A);
  LOADSUB(1, Bb);
  compute_sub(A0, A1, A2, A3, w1l, bwl, b2f, col, quad, YPTR(0));
  LOADSUB(2, A);
  compute_sub(Bb0, Bb1, Bb2, Bb3, w1l, bwl, b2f, col, quad, YPTR(1));
  LOADSUB(3, Bb);
  compute_sub(A0, A1, A2, A3, w1l, bwl, b2f, col, quad, YPTR(2));
  compute_sub(Bb0, Bb1, Bb2, Bb3, w1l, bwl, b2f, col, quad, YPTR(3));
#undef LOADSUB
#undef YPTR
}

// Kernel 3 (path A): transpose-combine. Block handles 32 rows x all 32 f:
// coalesced y reads (f-major), LDS transpose, coalesced float2 writes.
__global__ __launch_bounds__(256) void ContMlp_combine(
    const float* __restrict__ X, const float* __restrict__ yws,
    float* __restrict__ out) {
  __shared__ float yl[F_SZ][33];
  const int r0 = blockIdx.x * 32;
  const int t = threadIdx.x;
#pragma unroll
  for (int i = 0; i < 4; ++i) {
    int idx = t + 256 * i;            // 0..1023
    int f = idx >> 5, r = idx & 31;
    yl[f][r] = yws[(size_t)f * B_SZ + r0 + r];
  }
  __syncthreads();
#pragma unroll
  for (int i = 0; i < 4; ++i) {
    int idx = t + 256 * i;
    int r = idx >> 5, f = idx & 31;
    float2 o2 = make_float2(X[(size_t)(r0 + r) * F_SZ + f], yl[f][r]);
    *(float2*)(out + (size_t)(r0 + r) * (2 * F_SZ) + 2 * f) = o2;
  }
}

// Kernel 3 (path B fallback): scatter X into interleaved out.
__global__ __launch_bounds__(256) void ContMlp_xwrite(
    const float* __restrict__ X, float* __restrict__ out) {
  int idx = blockIdx.x * 256 + threadIdx.x;   // 0..B*F-1
  int r = idx >> 5, f = idx & 31;
  out[(size_t)r * (2 * F_SZ) + 2 * f] = X[idx];
}

extern "C" void kernel_launch(void* const* d_in, const int* in_sizes, int n_in,
                              void* d_out, int out_size, void* d_ws, size_t ws_size,
                              hipStream_t stream) {
  const float* X  = (const float*)d_in[0];
  const float* r_ = (const float*)d_in[1];
  const float* W1 = (const float*)d_in[2];
  const float* b1 = (const float*)d_in[3];
  const float* W2 = (const float*)d_in[4];
  const float* b2 = (const float*)d_in[5];
  float* out = (float*)d_out;

  const size_t w1t_bytes = (size_t)F_SZ * H_SZ * D_SZ * 2;  // 512 KB
  const size_t bw_off    = w1t_bytes;
  const size_t bw_bytes  = (size_t)F_SZ * H_SZ * 4;         // 16 KB
  const size_t y_off     = bw_off + bw_bytes;
  const size_t y_bytes   = (size_t)B_SZ * F_SZ * 4;         // 2 MB

  unsigned short* w1t = (unsigned short*)d_ws;
  unsigned int*   bw  = (unsigned int*)((char*)d_ws + bw_off);

  ContMlp_prep<<<F_SZ * 4, 256, 0, stream>>>(W1, b1, W2, w1t, bw);

  const bool pathA = ws_size >= y_off + y_bytes;
  if (pathA) {
    float* yws = (float*)((char*)d_ws + y_off);
    ContMlp_main<<<64 * F_SZ, 256, 0, stream>>>(r_, w1t, bw, b2, yws,
                                                B_SZ, 1, 0);
    ContMlp_combine<<<B_SZ / 32, 256, 0, stream>>>(X, yws, out);
  } else {
    ContMlp_main<<<64 * F_SZ, 256, 0, stream>>>(r_, w1t, bw, b2, out,
                                                2, 2 * F_SZ, 1);
    ContMlp_xwrite<<<(B_SZ * F_SZ) / 256, 256, 0, stream>>>(X, out);
  }
}